// Round 9
// baseline (3575.329 us; speedup 1.0000x reference)
//
#include <hip/hip_runtime.h>
#include <hip/hip_bf16.h>

#define Bsz 128
#define Tsz 1024
#define Dsz 128
#define Hsz 512
#define NBLK 128   // 8 bt-groups x 16 ks-blocks
#define NKC 20     // 640 / 32 K-chunks

typedef __attribute__((ext_vector_type(8))) short short8;
typedef __attribute__((ext_vector_type(4))) float f4;
typedef unsigned long long u64;

__device__ __forceinline__ short bf16_rne(float f) {
  unsigned u = __builtin_bit_cast(unsigned, f);
  u += 0x7fffu + ((u >> 16) & 1u);
  return (short)(u >> 16);
}
__device__ __forceinline__ float sigmoid_(float v) { return 1.f / (1.f + __expf(-v)); }
// tanh(x) = 1 - 2/(e^{2x}+1); saturates correctly for |x| large (exp->0 or inf)
__device__ __forceinline__ float tanh_fast(float v) {
  return 1.f - 2.f / (1.f + __expf(2.f * v));
}

// Persistent LSTM. Exchange protocol = frozen anchor shape (all-wave sleep-poll,
// per-wave h staging, barrier 1, trailing barrier + tx0 flag store).
// Round-8 delta: GROUP = 16 blocks x 32 h-cols (was 32 x 16).
//  - Mechanism: per-step group sync tail = max over 16 (not 32) blocks; group
//    h-read traffic halves (256 KB/step); flag line count 1 per group.
//  - Each wave computes TWO 16-col output tiles (wfragA/wfragB, 8 accums);
//    A_lds chunk read once, fed to both MFMAs -> LDS traffic unchanged.
//  - r7's transposed gate layout kept (no gates_lds, no barrier 2, shfl
//    combine); h stores now 16 B contiguous/lane, full 64-B line per row.
__global__ __launch_bounds__(256, 1) void lstm_persist(
    const float* __restrict__ x, const float* __restrict__ W_ih,
    const float* __restrict__ W_hh, const float* __restrict__ b_ih,
    const float* __restrict__ b_hh, const float* __restrict__ W_fc,
    const float* __restrict__ b_fc, float* __restrict__ out,
    int* flags, unsigned short* hb0, unsigned short* hb1)
{
  const int bx = blockIdx.x;
  const int bt = bx & 7, ks = bx >> 3;   // 16 ks-blocks per bt-group
  const int b0 = bt << 4, k0 = ks << 5;  // 32 h-cols per block
  const int tx = threadIdx.x;
  const int wave = tx >> 6, lane = tx & 63;
  const int m = lane & 15, quad = lane >> 4;
  const int k_l = tx & 15, b_l = tx >> 4;   // FC-tail ownership

  __shared__ short8 A_lds[NKC][64];      // 20 KB, pre-permuted A fragments
  __shared__ float fc_red[16][16];       // final FC reduction

  int* gflags = flags + bt * 16;         // 16 flags = 64 B = one line per group

  // ---- load W fragments into registers (once). ----
  // Wave w covers h-cols k0 + w*8 .. k0 + w*8 + 7 (two 4-col groups A/B).
  // Output col n (tile A): gate g = n>>2, h-col = colA = k0 + w*8 + (n&3).
  const int colA = k0 + wave * 8 + (m & 3);
  const int colB = colA + 4;
  short8 wfragA[NKC], wfragB[NKC];
  {
    const int jA = (m >> 2) * Hsz + colA;
    const int jB = (m >> 2) * Hsz + colB;
    #pragma unroll
    for (int kc = 0; kc < NKC; ++kc) {
      const int kk = kc * 32 + quad * 8;
      const float* srcA = (kk < Dsz) ? (W_ih + (size_t)jA * Dsz + kk)
                                     : (W_hh + (size_t)jA * Hsz + (kk - Dsz));
      const float* srcB = (kk < Dsz) ? (W_ih + (size_t)jB * Dsz + kk)
                                     : (W_hh + (size_t)jB * Hsz + (kk - Dsz));
      const f4* svA = (const f4*)srcA;
      f4 va0 = svA[0], va1 = svA[1];
      short8 wa;
      wa[0] = bf16_rne(va0[0]); wa[1] = bf16_rne(va0[1]);
      wa[2] = bf16_rne(va0[2]); wa[3] = bf16_rne(va0[3]);
      wa[4] = bf16_rne(va1[0]); wa[5] = bf16_rne(va1[1]);
      wa[6] = bf16_rne(va1[2]); wa[7] = bf16_rne(va1[3]);
      wfragA[kc] = wa;
      const f4* svB = (const f4*)srcB;
      f4 vb0 = svB[0], vb1 = svB[1];
      short8 wb;
      wb[0] = bf16_rne(vb0[0]); wb[1] = bf16_rne(vb0[1]);
      wb[2] = bf16_rne(vb0[2]); wb[3] = bf16_rne(vb0[3]);
      wb[4] = bf16_rne(vb1[0]); wb[5] = bf16_rne(vb1[1]);
      wb[6] = bf16_rne(vb1[2]); wb[7] = bf16_rne(vb1[3]);
      wfragB[kc] = wb;
    }
  }
  float biasA[4], biasB[4];
  #pragma unroll
  for (int g = 0; g < 4; ++g) {
    biasA[g] = b_ih[g * Hsz + colA] + b_hh[g * Hsz + colA];
    biasB[g] = b_ih[g * Hsz + colB] + b_hh[g * Hsz + colB];
  }
  float c_regA = 0.f, c_regB = 0.f;  // lane owns (row = quad*4+(m>>2), colA/colB)

  for (int t = 0; t < Tsz; ++t) {
    unsigned short* hnext = (t & 1) ? hb1 : hb0;
    const unsigned short* hprev = (t & 1) ? hb0 : hb1;

    // Issue x loads first: in flight (normal, L2-cached) while we poll.
    const f4* xv = (const f4*)(x + (size_t)(b0 + m) * (Tsz * Dsz)
                               + (size_t)t * Dsz + wave * 32 + quad * 8);
    f4 v0 = xv[0], v1 = xv[1];

    if (t > 0) {
      // all 4 waves poll the 16 group flags (lane&15 -> 4x replication)
      for (;;) {
        int f = __hip_atomic_load(gflags + (lane & 15),
                                  __ATOMIC_RELAXED, __HIP_MEMORY_SCOPE_AGENT);
        if (__all(f >= t)) break;
        __builtin_amdgcn_s_sleep(1);
      }
      // stage this wave's 4 h chunks from LLC (agent-scope loads, bypass L2)
      #pragma unroll
      for (int q = 0; q < 4; ++q) {
        const int kc = 4 + wave * 4 + q;
        const int kh = (kc - 4) * 32 + quad * 8;
        const u64* p = (const u64*)(hprev + (size_t)(b0 + m) * Hsz + kh);
        u64 lo = __hip_atomic_load(p,     __ATOMIC_RELAXED, __HIP_MEMORY_SCOPE_AGENT);
        u64 hi = __hip_atomic_load(p + 1, __ATOMIC_RELAXED, __HIP_MEMORY_SCOPE_AGENT);
        u64* dst = (u64*)&A_lds[kc][lane];
        dst[0] = lo; dst[1] = hi;
      }
    } else {
      short8 z = {0, 0, 0, 0, 0, 0, 0, 0};
      #pragma unroll
      for (int q = 0; q < 4; ++q) A_lds[4 + wave * 4 + q][lane] = z;
    }

    { // stage x chunk (kc = wave, K 0..127)
      short8 a;
      a[0] = bf16_rne(v0[0]); a[1] = bf16_rne(v0[1]);
      a[2] = bf16_rne(v0[2]); a[3] = bf16_rne(v0[3]);
      a[4] = bf16_rne(v1[0]); a[5] = bf16_rne(v1[1]);
      a[6] = bf16_rne(v1[2]); a[7] = bf16_rne(v1[3]);
      A_lds[wave][lane] = a;
    }
    __syncthreads();   // barrier 1: A_lds complete before any wave's MFMA reads

    // ---- K loop: 20 x ds_read_b128, each chunk feeds TWO mfma (tiles A,B)
    f4 a0 = {0.f,0.f,0.f,0.f}, a1 = {0.f,0.f,0.f,0.f};
    f4 a2 = {0.f,0.f,0.f,0.f}, a3 = {0.f,0.f,0.f,0.f};
    f4 c0 = {0.f,0.f,0.f,0.f}, c1 = {0.f,0.f,0.f,0.f};
    f4 c2 = {0.f,0.f,0.f,0.f}, c3 = {0.f,0.f,0.f,0.f};
    #pragma unroll
    for (int kc = 0; kc < NKC; kc += 4) {
      short8 f0 = A_lds[kc][lane],     f1 = A_lds[kc + 1][lane];
      short8 f2 = A_lds[kc + 2][lane], f3 = A_lds[kc + 3][lane];
      a0 = __builtin_amdgcn_mfma_f32_16x16x32_bf16(f0, wfragA[kc],     a0, 0, 0, 0);
      c0 = __builtin_amdgcn_mfma_f32_16x16x32_bf16(f0, wfragB[kc],     c0, 0, 0, 0);
      a1 = __builtin_amdgcn_mfma_f32_16x16x32_bf16(f1, wfragA[kc + 1], a1, 0, 0, 0);
      c1 = __builtin_amdgcn_mfma_f32_16x16x32_bf16(f1, wfragB[kc + 1], c1, 0, 0, 0);
      a2 = __builtin_amdgcn_mfma_f32_16x16x32_bf16(f2, wfragA[kc + 2], a2, 0, 0, 0);
      c2 = __builtin_amdgcn_mfma_f32_16x16x32_bf16(f2, wfragB[kc + 2], c2, 0, 0, 0);
      a3 = __builtin_amdgcn_mfma_f32_16x16x32_bf16(f3, wfragA[kc + 3], a3, 0, 0, 0);
      c3 = __builtin_amdgcn_mfma_f32_16x16x32_bf16(f3, wfragB[kc + 3], c3, 0, 0, 0);
    }
    f4 accA = (a0 + a1) + (a2 + a3);   // tile A: D[row=quad*4+r][n=m]
    f4 accB = (c0 + c1) + (c2 + c3);   // tile B

    { // ---- 4x4 transpose (lane bits[3:2] <-> reg idx) + combine, tiles A,B --
      const int g0b = (m >> 2) & 1, g1b = (m >> 3) & 1;
      float vA[4], vB[4];
      { // tile A
        float s1[4], w1[4];
        #pragma unroll
        for (int r = 0; r < 4; ++r) s1[r] = __shfl_xor(accA[r ^ 1], 4);
        #pragma unroll
        for (int r = 0; r < 4; ++r) w1[r] = ((r & 1) == g0b) ? accA[r] : s1[r];
        float s2[4];
        #pragma unroll
        for (int r = 0; r < 4; ++r) s2[r] = __shfl_xor(w1[r ^ 2], 8);
        #pragma unroll
        for (int r = 0; r < 4; ++r) vA[r] = (((r >> 1) & 1) == g1b) ? w1[r] : s2[r];
      }
      { // tile B
        float s1[4], w1[4];
        #pragma unroll
        for (int r = 0; r < 4; ++r) s1[r] = __shfl_xor(accB[r ^ 1], 4);
        #pragma unroll
        for (int r = 0; r < 4; ++r) w1[r] = ((r & 1) == g0b) ? accB[r] : s1[r];
        float s2[4];
        #pragma unroll
        for (int r = 0; r < 4; ++r) s2[r] = __shfl_xor(w1[r ^ 2], 8);
        #pragma unroll
        for (int r = 0; r < 4; ++r) vB[r] = (((r >> 1) & 1) == g1b) ? w1[r] : s2[r];
      }
      float iA = sigmoid_(vA[0] + biasA[0]), fA = sigmoid_(vA[1] + biasA[1]);
      float gA = tanh_fast(vA[2] + biasA[2]), oA = sigmoid_(vA[3] + biasA[3]);
      c_regA = fA * c_regA + iA * gA;
      float hA = oA * tanh_fast(c_regA);
      float iB = sigmoid_(vB[0] + biasB[0]), fB = sigmoid_(vB[1] + biasB[1]);
      float gB = tanh_fast(vB[2] + biasB[2]), oB = sigmoid_(vB[3] + biasB[3]);
      c_regB = fB * c_regB + iB * gB;
      float hB = oB * tanh_fast(c_regB);
      // pack 4 cols per tile into u64; lane (m&3)==0 stores 16 B contiguous.
      unsigned hbA = (unsigned)(unsigned short)bf16_rne(hA);
      unsigned loA = hbA | (__shfl_xor(hbA, 1) << 16);
      u64 bothA = ((u64)__shfl_xor(loA, 2) << 32) | (u64)loA;
      unsigned hbB = (unsigned)(unsigned short)bf16_rne(hB);
      unsigned loB = hbB | (__shfl_xor(hbB, 1) << 16);
      u64 bothB = ((u64)__shfl_xor(loB, 2) << 32) | (u64)loB;
      if ((m & 3) == 0) {
        const int brow = b0 + quad * 4 + (m >> 2);
        u64* p = (u64*)(hnext + (size_t)brow * Hsz + k0 + wave * 8);
        __hip_atomic_store(p,     bothA, __ATOMIC_RELAXED, __HIP_MEMORY_SCOPE_AGENT);
        __hip_atomic_store(p + 1, bothB, __ATOMIC_RELAXED, __HIP_MEMORY_SCOPE_AGENT);
      }
    }
    __syncthreads();               // drains vmcnt: all waves' h stores at LLC
    if (tx == 0)
      __hip_atomic_store(gflags + ks, t + 1, __ATOMIC_RELAXED, __HIP_MEMORY_SCOPE_AGENT);
  }

  // ---- final FC: out[b] = sigmoid(h_last . W_fc + b_fc), ks==0 blocks ----
  if (ks == 0) {
    for (;;) {
      int f = __hip_atomic_load(gflags + (lane & 15),
                                __ATOMIC_RELAXED, __HIP_MEMORY_SCOPE_AGENT);
      if (__all(f >= Tsz)) break;
      __builtin_amdgcn_s_sleep(1);
    }
    const unsigned short* hl = hb1;  // t=1023 (odd) wrote hb1
    const u64* p = (const u64*)(hl + (size_t)(b0 + b_l) * Hsz + k_l * 32);
    float partial = 0.f;
    #pragma unroll
    for (int q = 0; q < 8; ++q) {
      u64 v = __hip_atomic_load(p + q, __ATOMIC_RELAXED, __HIP_MEMORY_SCOPE_AGENT);
      #pragma unroll
      for (int e = 0; e < 4; ++e) {
        unsigned hv16 = (unsigned)((v >> (16 * e)) & 0xffffu);
        partial += __builtin_bit_cast(float, hv16 << 16) * W_fc[k_l * 32 + q * 4 + e];
      }
    }
    fc_red[b_l][k_l] = partial;
    __syncthreads();
    if (k_l == 0) {
      float s = b_fc[0];
      #pragma unroll
      for (int e = 0; e < 16; ++e) s += fc_red[b_l][e];
      out[b0 + b_l] = sigmoid_(s);
    }
  }
}

extern "C" void kernel_launch(void* const* d_in, const int* in_sizes, int n_in,
                              void* d_out, int out_size, void* d_ws, size_t ws_size,
                              hipStream_t stream) {
  const float* x    = (const float*)d_in[0];
  const float* W_ih = (const float*)d_in[1];
  const float* W_hh = (const float*)d_in[2];
  const float* b_ih = (const float*)d_in[3];
  const float* b_hh = (const float*)d_in[4];
  const float* W_fc = (const float*)d_in[5];
  const float* b_fc = (const float*)d_in[6];
  float* out = (float*)d_out;
  char* ws = (char*)d_ws;
  int* flags = (int*)ws;                                   // 8 groups x 16 flags
  unsigned short* hb0 = (unsigned short*)(ws + 4096);      // h double buffer (bf16)
  unsigned short* hb1 = (unsigned short*)(ws + 4096 + (size_t)Bsz * Hsz * 2);
  hipMemsetAsync(ws, 0, 4096, stream);                     // barrier flags := 0
  lstm_persist<<<NBLK, 256, 0, stream>>>(x, W_ih, W_hh, b_ih, b_hh, W_fc, b_fc,
                                         out, flags, hb0, hb1);
}

// Round 11
// 3138.824 us; speedup vs baseline: 1.1391x; 1.1391x over previous
//
#include <hip/hip_runtime.h>
#include <hip/hip_bf16.h>

#define Bsz 128
#define Tsz 1024
#define Dsz 128
#define Hsz 512
#define NBLK 256
#define NKC 20  // 640 / 32 K-chunks

typedef __attribute__((ext_vector_type(8))) short short8;
typedef __attribute__((ext_vector_type(4))) float f4;
typedef unsigned long long u64;

__device__ __forceinline__ short bf16_rne(float f) {
  unsigned u = __builtin_bit_cast(unsigned, f);
  u += 0x7fffu + ((u >> 16) & 1u);
  return (short)(u >> 16);
}
__device__ __forceinline__ float sigmoid_(float v) { return 1.f / (1.f + __expf(-v)); }
// tanh(x) = 1 - 2/(e^{2x}+1); saturates correctly for |x| large (exp->0 or inf)
__device__ __forceinline__ float tanh_fast(float v) {
  return 1.f - 2.f / (1.f + __expf(2.f * v));
}

// Persistent LSTM, fence-free coherence — FINAL: the verified anchor (r6,
// 3145.6us ~= 3123.5us session best; identical source). Ten rounds established:
//  - every protocol variant (tagged data r1, RMW release r2, wave0-poll r3,
//    arrival-order r4, fan-in/2 r9) regressed 13-173%;
//  - every intra-block cut (tanh_fast, 4-accum ILP r6; barrier-2+gates_lds
//    delete, bank-conflicts 8.4M->0 r7) was fully hidden => neutral;
//  - no-exchange decomposition is compute-limited ~2x worse (33.6 MFLOP/step
//    on one CU ~ 9900cy vs the 7300cy exchange floor).
// The kernel sits at the chip-wide synchronization-latency floor of a
// 1024-step serial recurrence: per step ~ store-drain + flag visibility +
// sleep-poll detect + agent-scope h gather + group straggler tail.
//  - h + flags exchanged via agent-scope RELAXED atomics (bypass L1/L2 -> LLC).
//    No buffer_wbl2 / buffer_inv per step => x stays cached in L2.
//  - 8 independent bt-groups of 32 blocks; bt = bx&7 (perf heuristic only;
//    agent scope keeps it correct under any placement).
//  - Ordering: __syncthreads() drains vmcnt before the flag store; readers issue
//    h loads only after the flag load returns (both hit the LLC coherence point).
__global__ __launch_bounds__(256, 1) void lstm_persist(
    const float* __restrict__ x, const float* __restrict__ W_ih,
    const float* __restrict__ W_hh, const float* __restrict__ b_ih,
    const float* __restrict__ b_hh, const float* __restrict__ W_fc,
    const float* __restrict__ b_fc, float* __restrict__ out,
    int* flags, unsigned short* hb0, unsigned short* hb1)
{
  const int bx = blockIdx.x;
  const int bt = bx & 7, ks = bx >> 3;   // group = same bt (same XCD if round-robin)
  const int b0 = bt << 4, k0 = ks << 4;
  const int tx = threadIdx.x;
  const int wave = tx >> 6, lane = tx & 63;
  const int m = lane & 15, quad = lane >> 4;
  const int k_l = tx & 15, b_l = tx >> 4;   // update-phase ownership: (b_l, k_l)

  __shared__ short8 A_lds[NKC][64];      // 20 KB, pre-permuted A fragments
  __shared__ f4 gates_lds[4][64];        // 4 KB, per-gate D fragments
  __shared__ float fc_red[16][16];       // final FC reduction

  int* gflags = flags + bt * 32;         // 32 flags = 128 B, one group

  // ---- load W fragments into registers (once). Wave w = gate w. ----
  short8 wfrag[NKC];
  {
    const int j = wave * Hsz + k0 + m;   // W row = output column n of B-operand
    #pragma unroll
    for (int kc = 0; kc < NKC; ++kc) {
      const int kk = kc * 32 + quad * 8;
      const float* src = (kk < Dsz) ? (W_ih + (size_t)j * Dsz + kk)
                                    : (W_hh + (size_t)j * Hsz + (kk - Dsz));
      const f4* sv = (const f4*)src;
      f4 v0 = sv[0], v1 = sv[1];
      short8 w;
      w[0] = bf16_rne(v0[0]); w[1] = bf16_rne(v0[1]);
      w[2] = bf16_rne(v0[2]); w[3] = bf16_rne(v0[3]);
      w[4] = bf16_rne(v1[0]); w[5] = bf16_rne(v1[1]);
      w[6] = bf16_rne(v1[2]); w[7] = bf16_rne(v1[3]);
      wfrag[kc] = w;
    }
  }
  float bias[4];
  #pragma unroll
  for (int g = 0; g < 4; ++g)
    bias[g] = b_ih[g * Hsz + k0 + k_l] + b_hh[g * Hsz + k0 + k_l];
  float c_reg = 0.f;

  for (int t = 0; t < Tsz; ++t) {
    unsigned short* hnext = (t & 1) ? hb1 : hb0;
    const unsigned short* hprev = (t & 1) ? hb0 : hb1;

    // Issue x loads first: in flight (normal, L2-cached) while we poll.
    const f4* xv = (const f4*)(x + (size_t)(b0 + m) * (Tsz * Dsz)
                               + (size_t)t * Dsz + wave * 32 + quad * 8);
    f4 v0 = xv[0], v1 = xv[1];

    if (t > 0) {
      // all 4 waves poll the 32 group flags (lanes 32..63 mirror 0..31)
      for (;;) {
        int f = __hip_atomic_load(gflags + (lane & 31),
                                  __ATOMIC_RELAXED, __HIP_MEMORY_SCOPE_AGENT);
        if (__all(f >= t)) break;
        __builtin_amdgcn_s_sleep(1);
      }
      // stage this wave's 4 h chunks from LLC (agent-scope loads, bypass L2)
      #pragma unroll
      for (int q = 0; q < 4; ++q) {
        const int kc = 4 + wave * 4 + q;
        const int kh = (kc - 4) * 32 + quad * 8;
        const u64* p = (const u64*)(hprev + (size_t)(b0 + m) * Hsz + kh);
        u64 lo = __hip_atomic_load(p,     __ATOMIC_RELAXED, __HIP_MEMORY_SCOPE_AGENT);
        u64 hi = __hip_atomic_load(p + 1, __ATOMIC_RELAXED, __HIP_MEMORY_SCOPE_AGENT);
        u64* dst = (u64*)&A_lds[kc][lane];
        dst[0] = lo; dst[1] = hi;
      }
    } else {
      short8 z = {0, 0, 0, 0, 0, 0, 0, 0};
      #pragma unroll
      for (int q = 0; q < 4; ++q) A_lds[4 + wave * 4 + q][lane] = z;
    }

    { // stage x chunk (kc = wave, K 0..127)
      short8 a;
      a[0] = bf16_rne(v0[0]); a[1] = bf16_rne(v0[1]);
      a[2] = bf16_rne(v0[2]); a[3] = bf16_rne(v0[3]);
      a[4] = bf16_rne(v1[0]); a[5] = bf16_rne(v1[1]);
      a[6] = bf16_rne(v1[2]); a[7] = bf16_rne(v1[3]);
      A_lds[wave][lane] = a;
    }
    __syncthreads();

    // ---- K loop: 20 x (ds_read_b128 + mfma), 4 accumulators for ILP
    f4 a0 = {0.f, 0.f, 0.f, 0.f}, a1 = {0.f, 0.f, 0.f, 0.f};
    f4 a2 = {0.f, 0.f, 0.f, 0.f}, a3 = {0.f, 0.f, 0.f, 0.f};
    #pragma unroll
    for (int kc = 0; kc < NKC; kc += 4) {
      a0 = __builtin_amdgcn_mfma_f32_16x16x32_bf16(A_lds[kc][lane],     wfrag[kc],     a0, 0, 0, 0);
      a1 = __builtin_amdgcn_mfma_f32_16x16x32_bf16(A_lds[kc + 1][lane], wfrag[kc + 1], a1, 0, 0, 0);
      a2 = __builtin_amdgcn_mfma_f32_16x16x32_bf16(A_lds[kc + 2][lane], wfrag[kc + 2], a2, 0, 0, 0);
      a3 = __builtin_amdgcn_mfma_f32_16x16x32_bf16(A_lds[kc + 3][lane], wfrag[kc + 3], a3, 0, 0, 0);
    }
    gates_lds[wave][lane] = (a0 + a1) + (a2 + a3);   // lane holds D[b=quad*4+r][n=lane&15]
    __syncthreads();

    { // ---- gate combine + state update: thread owns (b_l, k_l) ----
      const int lp = ((b_l >> 2) << 4) + k_l;  // lane holding row b_l
      const int r = b_l & 3;                   // reg index
      float pi = gates_lds[0][lp][r] + bias[0];
      float pf = gates_lds[1][lp][r] + bias[1];
      float pg = gates_lds[2][lp][r] + bias[2];
      float po = gates_lds[3][lp][r] + bias[3];
      float iv = sigmoid_(pi), fv = sigmoid_(pf), ov = sigmoid_(po);
      float gv = tanh_fast(pg);
      c_reg = fv * c_reg + iv * gv;
      float hv = ov * tanh_fast(c_reg);
      // pack two bf16 (k_l even|odd) into one u32 agent-scope store (no 16b atomics)
      unsigned hbits = (unsigned)(unsigned short)bf16_rne(hv);
      unsigned obits = __shfl_xor(hbits, 1);
      if ((k_l & 1) == 0) {
        unsigned packed = hbits | (obits << 16);
        unsigned* p = (unsigned*)(hnext + (size_t)(b0 + b_l) * Hsz + k0 + k_l);
        __hip_atomic_store(p, packed, __ATOMIC_RELAXED, __HIP_MEMORY_SCOPE_AGENT);
      }
    }
    __syncthreads();               // drains vmcnt: all waves' h stores at LLC
    if (tx == 0)
      __hip_atomic_store(gflags + ks, t + 1, __ATOMIC_RELAXED, __HIP_MEMORY_SCOPE_AGENT);
  }

  // ---- final FC: out[b] = sigmoid(h_last . W_fc + b_fc), ks==0 blocks ----
  if (ks == 0) {
    for (;;) {
      int f = __hip_atomic_load(gflags + (lane & 31),
                                __ATOMIC_RELAXED, __HIP_MEMORY_SCOPE_AGENT);
      if (__all(f >= Tsz)) break;
      __builtin_amdgcn_s_sleep(1);
    }
    const unsigned short* hl = hb1;  // t=1023 (odd) wrote hb1
    const u64* p = (const u64*)(hl + (size_t)(b0 + b_l) * Hsz + k_l * 32);
    float partial = 0.f;
    #pragma unroll
    for (int q = 0; q < 8; ++q) {
      u64 v = __hip_atomic_load(p + q, __ATOMIC_RELAXED, __HIP_MEMORY_SCOPE_AGENT);
      #pragma unroll
      for (int e = 0; e < 4; ++e) {
        unsigned hv16 = (unsigned)((v >> (16 * e)) & 0xffffu);
        partial += __builtin_bit_cast(float, hv16 << 16) * W_fc[k_l * 32 + q * 4 + e];
      }
    }
    fc_red[b_l][k_l] = partial;
    __syncthreads();
    if (k_l == 0) {
      float s = b_fc[0];
      #pragma unroll
      for (int e = 0; e < 16; ++e) s += fc_red[b_l][e];
      out[b0 + b_l] = sigmoid_(s);
    }
  }
}

extern "C" void kernel_launch(void* const* d_in, const int* in_sizes, int n_in,
                              void* d_out, int out_size, void* d_ws, size_t ws_size,
                              hipStream_t stream) {
  const float* x    = (const float*)d_in[0];
  const float* W_ih = (const float*)d_in[1];
  const float* W_hh = (const float*)d_in[2];
  const float* b_ih = (const float*)d_in[3];
  const float* b_hh = (const float*)d_in[4];
  const float* W_fc = (const float*)d_in[5];
  const float* b_fc = (const float*)d_in[6];
  float* out = (float*)d_out;
  char* ws = (char*)d_ws;
  int* flags = (int*)ws;                                   // 8 groups x 32 flags
  unsigned short* hb0 = (unsigned short*)(ws + 4096);      // h double buffer (bf16)
  unsigned short* hb1 = (unsigned short*)(ws + 4096 + (size_t)Bsz * Hsz * 2);
  hipMemsetAsync(ws, 0, 4096, stream);                     // barrier flags := 0
  lstm_persist<<<NBLK, 256, 0, stream>>>(x, W_ih, W_hh, b_ih, b_hh, W_fc, b_fc,
                                         out, flags, hb0, hb1);
}